// Round 1
// baseline (1035.513 us; speedup 1.0000x reference)
//
#include <hip/hip_runtime.h>

// FilterBasedTokenizer: X[16,50176,256] fp32, Wa[16,256,16] fp32
//   A = softmax_over_N(X @ Wa);  out = A^T @ X   -> [16,16,256] fp32
// Single pass over X (822 MB -> ~130 us roofline), bf16 MFMA for both GEMMs,
// exp without max-subtraction (|scores| <= ~8, safe in fp32).

#define BATCH 16
#define NTOK  50176
#define CH    256
#define LDIM  16
#define CHUNK 64
#define GPB   48                    // blocks per batch
#define NCHUNK (NTOK / CHUNK)       // 784

typedef __bf16 bf16x8 __attribute__((ext_vector_type(8)));
typedef float  f32x4  __attribute__((ext_vector_type(4)));

#define XS_STRIDE 264   // 64-token chunk rows, bf16, 528B row (16B aligned, +8 pad)
#define WT_STRIDE 264   // Wa^T rows
#define WK_STRIDE 72    // w^T rows (64 tokens + 8 pad), 144B row

// USE_PARTIALS: write per-block partial T/s to ws, reduce kernel sums (no atomics).
// Fallback (small ws): atomicAdd into a single [B][L][C] accumulator.
template <bool USE_PARTIALS>
__global__ __launch_bounds__(256, 3)
void tok_main(const float* __restrict__ X, const float* __restrict__ Wa,
              float* __restrict__ Tout, float* __restrict__ sout)
{
    __shared__ __align__(16) __bf16 Xs[CHUNK][XS_STRIDE];   // 33792 B
    __shared__ __align__(16) __bf16 Wt[LDIM][WT_STRIDE];    //  8448 B
    __shared__ __align__(16) __bf16 wT[LDIM][WK_STRIDE];    //  2304 B
    __shared__ float s_lds[LDIM];

    const int tid  = threadIdx.x;
    const int wave = tid >> 6;
    const int lane = tid & 63;
    const int quad = lane >> 4;
    const int l16  = lane & 15;

    const int b = blockIdx.x / GPB;
    const int g = blockIdx.x % GPB;

    // Stage Wa[b] (fp32 [c][l]) -> Wt bf16 [l][c]  (A-operand layout for phase A)
    {
        const float* wrow = Wa + ((size_t)b * CH + tid) * LDIM;
        #pragma unroll
        for (int l = 0; l < LDIM; ++l)
            Wt[l][tid] = (__bf16)wrow[l];
    }
    if (tid < LDIM) s_lds[tid] = 0.0f;

    f32x4 acc[4];
    #pragma unroll
    for (int t = 0; t < 4; ++t) acc[t] = (f32x4){0.f, 0.f, 0.f, 0.f};
    float s_acc[4] = {0.f, 0.f, 0.f, 0.f};

    const float* Xb = X + (size_t)b * NTOK * CH;

    for (int chunk = g; chunk < NCHUNK; chunk += GPB) {
        const float* Xc = Xb + (size_t)chunk * CHUNK * CH;
        __syncthreads();   // previous iteration's readers of Xs/wT are done
        // stage 64x256 fp32 -> bf16 LDS (coalesced float4 loads)
        #pragma unroll
        for (int j = 0; j < 16; ++j) {
            const int f   = j * 256 + tid;        // float4 index within chunk
            const int tok = f >> 6;               // 64 float4 per token row
            const int c4  = (f & 63) << 2;
            const float4 v = *(const float4*)(Xc + tok * CH + c4);
            __bf16* dst = &Xs[tok][c4];
            dst[0] = (__bf16)v.x; dst[1] = (__bf16)v.y;
            dst[2] = (__bf16)v.z; dst[3] = (__bf16)v.w;
        }
        __syncthreads();

        // phase A: D[l][tok] = Wa^T @ X^T for this wave's 16-token tile.
        // A-frag: Wt[l=lane&15][k=c], B-frag: Xs[tok=lane&15(+16*wave)][k=c] (both b128)
        f32x4 d = (f32x4){0.f, 0.f, 0.f, 0.f};
        #pragma unroll
        for (int ks = 0; ks < 8; ++ks) {
            const bf16x8 a  = *(const bf16x8*)&Wt[l16][ks * 32 + quad * 8];
            const bf16x8 bb = *(const bf16x8*)&Xs[wave * 16 + l16][ks * 32 + quad * 8];
            d = __builtin_amdgcn_mfma_f32_16x16x32_bf16(a, bb, d, 0, 0, 0);
        }
        // D layout: row l = quad*4+r, col tok = lane&15. exp (no max-sub; |A|<~8)
        #pragma unroll
        for (int r = 0; r < 4; ++r) {
            const float e = __expf(d[r]);
            s_acc[r] += e;
            wT[quad * 4 + r][wave * 16 + l16] = (__bf16)e;
        }
        __syncthreads();

        // phase B: T[l][c] += w^T[l][n] @ X[n][c].  K = n (64 -> 2 ksteps).
        // A-frag: wT[l=lane&15][k=n] (b128); B-frag: X[n][c=lane&15+16*ct] -> u16 gather
        #pragma unroll
        for (int ks = 0; ks < 2; ++ks) {
            const bf16x8 a = *(const bf16x8*)&wT[l16][ks * 32 + quad * 8];
            #pragma unroll
            for (int t = 0; t < 4; ++t) {
                const int c = (wave * 4 + t) * 16 + l16;
                bf16x8 bb;
                #pragma unroll
                for (int j = 0; j < 8; ++j)
                    bb[j] = Xs[ks * 32 + quad * 8 + j][c];
                acc[t] = __builtin_amdgcn_mfma_f32_16x16x32_bf16(a, bb, acc[t], 0, 0, 0);
            }
        }
    }

    // block-level reduce of sum-of-exp per l
    #pragma unroll
    for (int r = 0; r < 4; ++r)
        atomicAdd(&s_lds[quad * 4 + r], s_acc[r]);
    __syncthreads();

    if (USE_PARTIALS) {
        if (tid < LDIM)
            sout[((size_t)b * GPB + g) * LDIM + tid] = s_lds[tid];
        float* Tb = Tout + ((size_t)b * GPB + g) * LDIM * CH;
        #pragma unroll
        for (int t = 0; t < 4; ++t) {
            const int c = (wave * 4 + t) * 16 + l16;
            #pragma unroll
            for (int r = 0; r < 4; ++r)
                Tb[(quad * 4 + r) * CH + c] = acc[t][r];
        }
    } else {
        if (tid < LDIM) atomicAdd(&sout[b * LDIM + tid], s_lds[tid]);
        float* Tb = Tout + (size_t)b * LDIM * CH;
        #pragma unroll
        for (int t = 0; t < 4; ++t) {
            const int c = (wave * 4 + t) * 16 + l16;
            #pragma unroll
            for (int r = 0; r < 4; ++r)
                atomicAdd(&Tb[(quad * 4 + r) * CH + c], acc[t][r]);
        }
    }
}

__global__ void tok_reduce_part(const float* __restrict__ Tp, const float* __restrict__ sp,
                                float* __restrict__ out)
{
    const int bl = blockIdx.x;          // b*16 + l
    const int c  = threadIdx.x;         // 0..255
    const int b = bl >> 4, l = bl & 15;
    float sum = 0.f, st = 0.f;
    for (int g = 0; g < GPB; ++g) {
        sum += Tp[(((size_t)b * GPB + g) * LDIM + l) * CH + c];
        st  += sp[((size_t)b * GPB + g) * LDIM + l];
    }
    out[(size_t)bl * CH + c] = sum / st;
}

__global__ void tok_reduce_atomic(const float* __restrict__ Tacc, const float* __restrict__ sacc,
                                  float* __restrict__ out)
{
    const int bl = blockIdx.x;
    const int c  = threadIdx.x;
    out[(size_t)bl * CH + c] = Tacc[(size_t)bl * CH + c] / sacc[bl];
}

extern "C" void kernel_launch(void* const* d_in, const int* in_sizes, int n_in,
                              void* d_out, int out_size, void* d_ws, size_t ws_size,
                              hipStream_t stream)
{
    const float* X  = (const float*)d_in[0];
    const float* Wa = (const float*)d_in[1];
    float* out = (float*)d_out;

    const size_t part_elems = (size_t)BATCH * GPB * LDIM * CH;   // 3,145,728
    const size_t sp_elems   = (size_t)BATCH * GPB * LDIM;        // 12,288
    const size_t need_part  = (part_elems + sp_elems) * sizeof(float);  // ~12.63 MB

    if (ws_size >= need_part) {
        float* Tp = (float*)d_ws;
        float* sp = Tp + part_elems;
        tok_main<true><<<BATCH * GPB, 256, 0, stream>>>(X, Wa, Tp, sp);
        tok_reduce_part<<<BATCH * LDIM, CH, 0, stream>>>(Tp, sp, out);
    } else {
        float* Tacc = (float*)d_ws;                    // [16][16][256]
        float* sacc = Tacc + (size_t)BATCH * LDIM * CH;
        hipMemsetAsync(d_ws, 0,
                       ((size_t)BATCH * LDIM * CH + BATCH * LDIM) * sizeof(float), stream);
        tok_main<false><<<BATCH * GPB, 256, 0, stream>>>(X, Wa, Tacc, sacc);
        tok_reduce_atomic<<<BATCH * LDIM, CH, 0, stream>>>(Tacc, sacc, out);
    }
}

// Round 2
// 1022.992 us; speedup vs baseline: 1.0122x; 1.0122x over previous
//
#include <hip/hip_runtime.h>

// FilterBasedTokenizer: X[16,50176,256] fp32, Wa[16,256,16] fp32
//   A = softmax_over_N(X @ Wa);  out = A^T @ X   -> [16,16,256] fp32
// Single pass over X (822 MB -> ~130 us roofline), bf16 MFMA for both GEMMs.
// R2: register-prefetch pipeline (overlap next chunk's HBM loads with compute),
//     Wa A-frags hoisted to registers (loop-invariant).

#define BATCH 16
#define NTOK  50176
#define CH    256
#define LDIM  16
#define CHUNK 64
#define GPB   48                    // blocks per batch -> 768 blocks = 3/CU
#define NCHUNK (NTOK / CHUNK)       // 784

typedef __bf16 bf16x8 __attribute__((ext_vector_type(8)));
typedef __bf16 bf16x4 __attribute__((ext_vector_type(4)));
typedef float  f32x4  __attribute__((ext_vector_type(4)));

#define XS_STRIDE 264   // 132 dwords/row: phase-A b128 reads conflict-free,
                        // phase-B gather 4-way (measured-cheap, 1.58x)
#define WK_STRIDE 72

template <bool USE_PARTIALS>
__global__ __launch_bounds__(256, 3)
void tok_main(const float* __restrict__ X, const float* __restrict__ Wa,
              float* __restrict__ Tout, float* __restrict__ sout)
{
    __shared__ __align__(16) __bf16 Xs[CHUNK][XS_STRIDE];   // 33792 B
    __shared__ __align__(16) __bf16 Wt[LDIM][CH + 8];       //  8448 B
    __shared__ __align__(16) __bf16 wT[LDIM][WK_STRIDE];    //  2304 B
    __shared__ float s_lds[LDIM];

    const int tid  = threadIdx.x;
    const int wave = tid >> 6;
    const int lane = tid & 63;
    const int quad = lane >> 4;
    const int l16  = lane & 15;

    const int b = blockIdx.x / GPB;
    const int g = blockIdx.x % GPB;

    // Stage Wa[b] (fp32 [c][l]) -> Wt bf16 [l][c], one-time
    {
        const float* wrow = Wa + ((size_t)b * CH + tid) * LDIM;
        #pragma unroll
        for (int l = 0; l < LDIM; ++l)
            Wt[l][tid] = (__bf16)wrow[l];
    }
    if (tid < LDIM) s_lds[tid] = 0.0f;
    __syncthreads();

    // Hoist loop-invariant phase-A A-frags: Wa^T[l=l16][k=ks*32+quad*8..+7]
    bf16x8 a_w[8];
    #pragma unroll
    for (int ks = 0; ks < 8; ++ks)
        a_w[ks] = *(const bf16x8*)&Wt[l16][ks * 32 + quad * 8];

    f32x4 acc[4];
    #pragma unroll
    for (int t = 0; t < 4; ++t) acc[t] = (f32x4){0.f, 0.f, 0.f, 0.f};
    float s_acc[4] = {0.f, 0.f, 0.f, 0.f};

    const float* Xb = X + (size_t)b * NTOK * CH;

    // ---- software pipeline: prefetch chunk g into registers ----
    f32x4 buf[16];   // wave w, j: row j*4+w, lane covers float4 idx = lane
    int chunk = g;
    {
        const float* Xc = Xb + (size_t)chunk * CHUNK * CH + wave * CH + lane * 4;
        #pragma unroll
        for (int j = 0; j < 16; ++j)
            buf[j] = *(const f32x4*)(Xc + (size_t)j * 4 * CH);
    }

    while (chunk < NCHUNK) {
        __syncthreads();   // previous iteration's readers of Xs/wT done
        // regs -> bf16 LDS (b64 stores, wave writes full rows)
        #pragma unroll
        for (int j = 0; j < 16; ++j) {
            bf16x4 o;
            o[0] = (__bf16)buf[j][0]; o[1] = (__bf16)buf[j][1];
            o[2] = (__bf16)buf[j][2]; o[3] = (__bf16)buf[j][3];
            *(bf16x4*)&Xs[j * 4 + wave][lane * 4] = o;
        }
        __syncthreads();

        // issue next chunk's global loads NOW; compute below hides the latency
        const int next = chunk + GPB;
        if (next < NCHUNK) {
            const float* Xc = Xb + (size_t)next * CHUNK * CH + wave * CH + lane * 4;
            #pragma unroll
            for (int j = 0; j < 16; ++j)
                buf[j] = *(const f32x4*)(Xc + (size_t)j * 4 * CH);
        }

        // phase A: D[l][tok] = Wa^T @ X^T for this wave's 16-token tile
        f32x4 d = (f32x4){0.f, 0.f, 0.f, 0.f};
        #pragma unroll
        for (int ks = 0; ks < 8; ++ks) {
            const bf16x8 bb = *(const bf16x8*)&Xs[wave * 16 + l16][ks * 32 + quad * 8];
            d = __builtin_amdgcn_mfma_f32_16x16x32_bf16(a_w[ks], bb, d, 0, 0, 0);
        }
        // D: row l = quad*4+r, col tok = l16. exp (no max-sub; |scores| < ~8)
        #pragma unroll
        for (int r = 0; r < 4; ++r) {
            const float e = __expf(d[r]);
            s_acc[r] += e;
            wT[quad * 4 + r][wave * 16 + l16] = (__bf16)e;
        }
        __syncthreads();

        // phase B: T[l][c] += w^T[l][n] @ X[n][c]
        #pragma unroll
        for (int ks = 0; ks < 2; ++ks) {
            const bf16x8 a = *(const bf16x8*)&wT[l16][ks * 32 + quad * 8];
            #pragma unroll
            for (int t = 0; t < 4; ++t) {
                const int c = (wave * 4 + t) * 16 + l16;
                bf16x8 bb;
                #pragma unroll
                for (int j = 0; j < 8; ++j)
                    bb[j] = Xs[ks * 32 + quad * 8 + j][c];
                acc[t] = __builtin_amdgcn_mfma_f32_16x16x32_bf16(a, bb, acc[t], 0, 0, 0);
            }
        }
        chunk = next;
    }

    // block-level reduce of sum-of-exp per l
    #pragma unroll
    for (int r = 0; r < 4; ++r)
        atomicAdd(&s_lds[quad * 4 + r], s_acc[r]);
    __syncthreads();

    if (USE_PARTIALS) {
        if (tid < LDIM)
            sout[((size_t)b * GPB + g) * LDIM + tid] = s_lds[tid];
        float* Tb = Tout + ((size_t)b * GPB + g) * LDIM * CH;
        #pragma unroll
        for (int t = 0; t < 4; ++t) {
            const int c = (wave * 4 + t) * 16 + l16;
            #pragma unroll
            for (int r = 0; r < 4; ++r)
                Tb[(quad * 4 + r) * CH + c] = acc[t][r];
        }
    } else {
        if (tid < LDIM) atomicAdd(&sout[b * LDIM + tid], s_lds[tid]);
        float* Tb = Tout + (size_t)b * LDIM * CH;
        #pragma unroll
        for (int t = 0; t < 4; ++t) {
            const int c = (wave * 4 + t) * 16 + l16;
            #pragma unroll
            for (int r = 0; r < 4; ++r)
                atomicAdd(&Tb[(quad * 4 + r) * CH + c], acc[t][r]);
        }
    }
}

__global__ void tok_reduce_part(const float* __restrict__ Tp, const float* __restrict__ sp,
                                float* __restrict__ out)
{
    const int bl = blockIdx.x;          // b*16 + l
    const int c  = threadIdx.x;         // 0..255
    const int b = bl >> 4, l = bl & 15;
    float sum = 0.f, st = 0.f;
    for (int g = 0; g < GPB; ++g) {
        sum += Tp[(((size_t)b * GPB + g) * LDIM + l) * CH + c];
        st  += sp[((size_t)b * GPB + g) * LDIM + l];
    }
    out[(size_t)bl * CH + c] = sum / st;
}

__global__ void tok_reduce_atomic(const float* __restrict__ Tacc, const float* __restrict__ sacc,
                                  float* __restrict__ out)
{
    const int bl = blockIdx.x;
    const int c  = threadIdx.x;
    out[(size_t)bl * CH + c] = Tacc[(size_t)bl * CH + c] / sacc[bl];
}

extern "C" void kernel_launch(void* const* d_in, const int* in_sizes, int n_in,
                              void* d_out, int out_size, void* d_ws, size_t ws_size,
                              hipStream_t stream)
{
    const float* X  = (const float*)d_in[0];
    const float* Wa = (const float*)d_in[1];
    float* out = (float*)d_out;

    const size_t part_elems = (size_t)BATCH * GPB * LDIM * CH;   // 3,145,728
    const size_t sp_elems   = (size_t)BATCH * GPB * LDIM;        // 12,288
    const size_t need_part  = (part_elems + sp_elems) * sizeof(float);  // ~12.63 MB

    if (ws_size >= need_part) {
        float* Tp = (float*)d_ws;
        float* sp = Tp + part_elems;
        tok_main<true><<<BATCH * GPB, 256, 0, stream>>>(X, Wa, Tp, sp);
        tok_reduce_part<<<BATCH * LDIM, CH, 0, stream>>>(Tp, sp, out);
    } else {
        float* Tacc = (float*)d_ws;                    // [16][16][256]
        float* sacc = Tacc + (size_t)BATCH * LDIM * CH;
        hipMemsetAsync(d_ws, 0,
                       ((size_t)BATCH * LDIM * CH + BATCH * LDIM) * sizeof(float), stream);
        tok_main<false><<<BATCH * GPB, 256, 0, stream>>>(X, Wa, Tacc, sacc);
        tok_reduce_atomic<<<BATCH * LDIM, CH, 0, stream>>>(Tacc, sacc, out);
    }
}